// Round 5
// baseline (92.527 us; speedup 1.0000x reference)
//
#include <hip/hip_runtime.h>
#include <hip/hip_bf16.h>

// out[b, 2t+r, c*128+d] = normed outer product of x[b,t,:] with itself.
// ||flatten(w*x⊗x)||_2 = |w| * (Σ x_c^2)  => per-frame: 128-elem sum of squares
// + rank-1 outer product streamed twice (UpSampling1D repeat).
// Pure HBM-write-bound: 512 MiB writes, 2 MiB reads.
//
// Round 5: FPB=8 (512 blocks = 2/CU exact) — halve block-boundary count again.
// R3->R4 (FPB 1->4) gave +2.3%; testing the residual of the same effect.

#define C 128
#define CC (C * C)       // 16384
#define CC4 (CC / 4)     // 4096 float4 per time-row
#define NTHREADS 256
#define FPB 8            // frames per block
#define EPS 1e-12f

typedef float f32x4 __attribute__((ext_vector_type(4)));

__global__ __launch_bounds__(NTHREADS) void frame_outer_kernel(
    const float* __restrict__ x,   // (BT, 128)
    const float* __restrict__ w,   // (1,)
    float* __restrict__ out)       // (BT*2, 16384)
{
    __shared__ __align__(16) float xs[FPB][C];
    __shared__ float par[4 * FPB / 2];   // par[4*j + wid], load j covers rows 2j,2j+1

    const int tid = threadIdx.x;
    const int wid = tid >> 6;
    const int frame0 = blockIdx.x * FPB;
    const float* __restrict__ xr = x + (size_t)frame0 * C;

    // Load FPB rows (FPB*128 floats) with 256 threads: FPB/2 elements each.
    // Load j covers elements [256j, 256j+255] = rows 2j, 2j+1.
    float v[FPB / 2];
    float pp[FPB / 2];
    #pragma unroll
    for (int j = 0; j < FPB / 2; ++j) {
        v[j] = xr[tid + 256 * j];
        ((float*)xs)[tid + 256 * j] = v[j];
        pp[j] = v[j] * v[j];
    }
    // Each wave (64 lanes) lies within one half-row; reduce all loads in lockstep.
    #pragma unroll
    for (int off = 32; off > 0; off >>= 1) {
        #pragma unroll
        for (int j = 0; j < FPB / 2; ++j)
            pp[j] += __shfl_down(pp[j], off);
    }
    if ((tid & 63) == 0) {
        #pragma unroll
        for (int j = 0; j < FPB / 2; ++j)
            par[4 * j + wid] = pp[j];
    }
    __syncthreads();   // xs[] and par[] ready

    const float wv = w[0];
    float wrs[FPB];
    #pragma unroll
    for (int fi = 0; fi < FPB; ++fi) {
        const float S = par[2 * fi] + par[2 * fi + 1];  // two half-row wave sums
        const float ws = wv * S;
        wrs[fi] = wv * rsqrtf(fmaxf(ws * ws, EPS));
    }

    // Stream stores: for each frame, out[c*128+d] = (wrs*xs[c]) * xs[d],
    // written to time rows 2t and 2t+1.
    const int d4 = tid & 31;   // float4 column — fixed per thread
    #pragma unroll
    for (int fi = 0; fi < FPB; ++fi) {
        const f32x4 xv = ((const f32x4*)xs[fi])[d4];
        const float a0 = wrs[fi];
        float* __restrict__ obase = out + (size_t)(frame0 + fi) * 2 * CC;
        f32x4* __restrict__ o0 = (f32x4*)obase;
        f32x4* __restrict__ o1 = (f32x4*)(obase + CC);
        #pragma unroll
        for (int k = 0; k < CC4 / NTHREADS; ++k) {   // 16 iterations
            const int i = k * NTHREADS + tid;
            const int c = i >> 5;                    // broadcast LDS read (2 addrs/wave)
            const float a = a0 * xs[fi][c];
            f32x4 r = a * xv;
            o0[i] = r;
            o1[i] = r;
        }
    }
}

extern "C" void kernel_launch(void* const* d_in, const int* in_sizes, int n_in,
                              void* d_out, int out_size, void* d_ws, size_t ws_size,
                              hipStream_t stream) {
    const float* x = (const float*)d_in[0];
    const float* w = (const float*)d_in[1];
    float* out = (float*)d_out;

    const int BT = in_sizes[0] / C;          // 4096 frames
    const int nblocks = BT / FPB;            // 512 blocks = 2 per CU
    frame_outer_kernel<<<nblocks, NTHREADS, 0, stream>>>(x, w, out);
}